// Round 6
// baseline (243.059 us; speedup 1.0000x reference)
//
#include <hip/hip_runtime.h>
#include <math.h>

#define B_DIM 2
#define S_DIM 2048
#define D_DIM 1024
#define H_NUM 16
#define DH    64
#define M_DIM (B_DIM * S_DIM) /* 4096 */

typedef __attribute__((ext_vector_type(8))) short short8;
typedef __attribute__((ext_vector_type(4))) short short4v;
typedef __attribute__((ext_vector_type(4))) float float4v;
typedef __attribute__((ext_vector_type(4))) unsigned short ushort4v;
typedef unsigned short ushort;

static __device__ __forceinline__ ushort f2bf(float f) {
    unsigned u = __float_as_uint(f);
    u += 0x7fffu + ((u >> 16) & 1u);
    return (ushort)(u >> 16);
}

static __device__ __forceinline__ float fexp2(float x) {
#if __has_builtin(__builtin_amdgcn_exp2f)
    return __builtin_amdgcn_exp2f(x);
#else
    return exp2f(x);
#endif
}

// 2 f32 -> 2 bf16 in one u32, lo half = first arg. Ordering PROVEN on this
// harness: rounds 3 (cvt_pk) and 4 (explicit lo|hi<<16 bit-ops) produced
// bit-identical outputs.
static __device__ __forceinline__ unsigned cvtpk_bf16(float lo, float hi) {
    unsigned r;
    asm("v_cvt_pk_bf16_f32 %0, %1, %2" : "=v"(r) : "v"(lo), "v"(hi));
    return r;
}

static __device__ __forceinline__ void gload_lds16(const void* g, void* l) {
    __builtin_amdgcn_global_load_lds(
        (const __attribute__((address_space(1))) void*)g,
        (__attribute__((address_space(3))) void*)l, 16, 0, 0);
}

// ---------------------------------------------------------------------------
// Fused fp32 -> bf16 cast of ALL five tensors in one launch.
// dst layout (contiguous in ws): xh[4M] | wq[1M] | wk[1M] | wv[1M] | wo[1M]
// ---------------------------------------------------------------------------
__global__ __launch_bounds__(256)
void cast_all(const float* __restrict__ x,  const float* __restrict__ wq,
              const float* __restrict__ wk, const float* __restrict__ wv,
              const float* __restrict__ wo, ushort* __restrict__ dst)
{
    const int i = blockIdx.x * 256 + threadIdx.x;   // 0 .. 2M-1 (float4 units)
    const float4* s;
    int off;
    if      (i < 1048576) { s = (const float4*)x;  off = 0;       }
    else if (i < 1310720) { s = (const float4*)wq; off = 1048576; }
    else if (i < 1572864) { s = (const float4*)wk; off = 1310720; }
    else if (i < 1835008) { s = (const float4*)wv; off = 1572864; }
    else                  { s = (const float4*)wo; off = 1835008; }
    const float4 v = s[i - off];
    ushort4v o;
    o[0] = f2bf(v.x); o[1] = f2bf(v.y); o[2] = f2bf(v.z); o[3] = f2bf(v.w);
    ((ushort4v*)dst)[i] = o;
}

// ---------------------------------------------------------------------------
// bf16 MFMA GEMM, m97 structure: 128x128 tile, BK=32, global_load_lds w=16,
// 4 waves in 2x2, each wave 64x64 via 4x4 grid of 16x16x32 MFMAs.
// A:[M=4096, K=1024] bf16 row-major. B:[N, K=1024] bf16 row-major.
// mode 0 (N=3072, fused QKV): n>>10 selects dst: 0->Qh [B,H,S,Dh]
//        (PRE-SCALED by 0.125*log2e for base-2 online softmax),
//        1->Kh [B,H,S,Dh], 2->Vt [B,H,Dh,S]; all bf16.
// mode 1 (N=1024, out proj): fp32 out[m*1024+n] = acc + bias[n].
// ---------------------------------------------------------------------------
__global__ __launch_bounds__(256)
void gemm_bf16(const ushort* __restrict__ A, const ushort* __restrict__ B,
               ushort* __restrict__ Qh, ushort* __restrict__ Kh,
               ushort* __restrict__ Vt, float* __restrict__ Of,
               const float* __restrict__ bias, int mode)
{
    __shared__ ushort Asm[128 * 32];   // [row][k], 64B rows, lane-order (no pad!)
    __shared__ ushort Bsm[128 * 32];

    const int K  = 1024;
    const int n0 = blockIdx.x * 128;
    const int m0 = blockIdx.y * 128;
    const int t    = threadIdx.x;
    const int w    = t >> 6;
    const int lane = t & 63;
    const int n    = lane & 15;
    const int quad = lane >> 4;
    const int wm = w >> 1, wn = w & 1;

    const int srow = w * 32 + (lane >> 2);
    const int skel = (lane & 3) * 8;

    float4v acc[4][4];
#pragma unroll
    for (int mt = 0; mt < 4; ++mt)
#pragma unroll
        for (int nt = 0; nt < 4; ++nt) acc[mt][nt] = (float4v){0.f, 0.f, 0.f, 0.f};

    for (int kt = 0; kt < K; kt += 32) {
#pragma unroll
        for (int i = 0; i < 2; ++i) {
            gload_lds16(&A[(size_t)(m0 + srow + i * 16) * K + kt + skel],
                        &Asm[(w * 2 + i) * 512]);
            gload_lds16(&B[(size_t)(n0 + srow + i * 16) * K + kt + skel],
                        &Bsm[(w * 2 + i) * 512]);
        }
        __syncthreads();

        short8 af[4], bfr[4];
#pragma unroll
        for (int mt = 0; mt < 4; ++mt)
            af[mt] = *(const short8*)&Asm[(wm * 64 + mt * 16 + n) * 32 + quad * 8];
#pragma unroll
        for (int nt = 0; nt < 4; ++nt)
            bfr[nt] = *(const short8*)&Bsm[(wn * 64 + nt * 16 + n) * 32 + quad * 8];

#pragma unroll
        for (int mt = 0; mt < 4; ++mt)
#pragma unroll
            for (int nt = 0; nt < 4; ++nt)
                acc[mt][nt] = __builtin_amdgcn_mfma_f32_16x16x32_bf16(
                    af[mt], bfr[nt], acc[mt][nt], 0, 0, 0);
        __syncthreads();
    }

    if (mode == 0) {
        const int wid = n0 >> 10;           // 0=Q 1=K 2=V (constant per block)
        ushort* dstQK = (wid == 0) ? Qh : Kh;
        const float qs = (wid == 0) ? 0.1803368801f : 1.0f;  // 0.125*log2(e)
#pragma unroll
        for (int mt = 0; mt < 4; ++mt) {
            const int m = m0 + wm * 64 + mt * 16 + quad * 4;   // +r
            const int b = m >> 11, s = m & (S_DIM - 1);
#pragma unroll
            for (int nt = 0; nt < 4; ++nt) {
                const int ng = (n0 & 1023) + wn * 64 + nt * 16 + n;
                const int h = ng >> 6, d = ng & 63;
                const int bh = b * H_NUM + h;
                if (wid < 2) {
#pragma unroll
                    for (int r = 0; r < 4; ++r)
                        dstQK[(((size_t)bh * S_DIM + s + r) << 6) + d] =
                            f2bf(acc[mt][nt][r] * qs);
                } else {
                    ushort4v p;
#pragma unroll
                    for (int r = 0; r < 4; ++r) p[r] = f2bf(acc[mt][nt][r]);
                    *(ushort4v*)&Vt[(((size_t)bh * DH + d) << 11) + s] = p;
                }
            }
        }
    } else {
#pragma unroll
        for (int mt = 0; mt < 4; ++mt) {
            const int m = m0 + wm * 64 + mt * 16 + quad * 4;
#pragma unroll
            for (int nt = 0; nt < 4; ++nt) {
                const int ng = n0 + wn * 64 + nt * 16 + n;
                const float bv = bias[ng];
#pragma unroll
                for (int r = 0; r < 4; ++r)
                    Of[(size_t)(m + r) * D_DIM + ng] = acc[mt][nt][r] + bv;
            }
        }
    }
}

// ---------------------------------------------------------------------------
// MFMA flash attention, swapped-QK^T, fully LOCAL P->PV handoff (round 5,
// verified), with two VALU/occupancy changes:
//  - P packing via v_cvt_pk_bf16_f32 (1 instr/dword; ordering proven
//    bit-identical to explicit lo|hi<<16 in rounds 3/4) -- deletes ~128
//    VALU inst per kb per wave.
//  - 16 q-rows per wave, 1024 blocks = 4 blocks/CU = 16 waves/CU, which is
//    exactly the VGPR-allowed occupancy cap. (Round-1's regression does not
//    apply: K/V are now block-shared LDS, per-wave compute halves cleanly.)
// Defer-max (THR=8, base-2); Q pre-scaled by 0.125*log2e.
// ---------------------------------------------------------------------------
__global__ __launch_bounds__(256)
void attn_mfma(const ushort* __restrict__ Qh, const ushort* __restrict__ Kh,
               const ushort* __restrict__ Vt, ushort* __restrict__ Yh)
{
    __shared__ ushort Ksm[2][64 * 64];   // [buf][key 64][d 64] granule-swizzled
    __shared__ ushort Vsm[2][64 * 64];   // [buf][d 64][key 64] granule-swizzled

    const int w    = threadIdx.x >> 6;
    const int lane = threadIdx.x & 63;
    const int n    = lane & 15;
    const int quad = lane >> 4;

    const int wave_id = blockIdx.x * 4 + w;
    const int bh    = wave_id >> 7;          // 128 waves per (b,h); uniform/block
    const int qbase = (wave_id & 127) * 16;
    const int b     = bh >> 4;
    const int h     = bh & (H_NUM - 1);

    const ushort* Qb = Qh + (((size_t)bh * S_DIM) << 6);
    const ushort* Kb = Kh + (((size_t)bh * S_DIM) << 6);
    const ushort* Vb = Vt + (((size_t)bh * DH) << 11);

    // staging: lane l covers row sub-index l>>3, 16B granule (l&7), source
    // granule pre-swizzled (gload_lds dst must stay linear).
    const int l8 = lane >> 3;
    const int sg = (lane & 7) ^ l8;

    short8 qa[2];   // B-frag: lane holds Q[q = qbase+n][d = kc*32+quad*8 ..]
#pragma unroll
    for (int kc = 0; kc < 2; ++kc)
        qa[kc] = *(const short8*)&Qb[((size_t)(qbase + n) << 6) + kc * 32 + quad * 8];

    float4v O[4];          // O[nt][r]: q = qbase+quad*4+r, d = nt*16+n
    float   mrow, lrow;    // per-lane: q = qbase + n (uniform over quads)
#pragma unroll
    for (int nt = 0; nt < 4; ++nt) O[nt] = (float4v){0.f, 0.f, 0.f, 0.f};
    mrow = -1e30f; lrow = 0.f;

    // K fragment-read offsets (ushort units): logical granule g at row rr is
    // stored at physical g ^ (rr&7); rr&7 == n&7 for rr = ct*16 + n.
    const int fswz[2] = { ((0 * 4 + quad) ^ (n & 7)) * 8,
                          ((1 * 4 + quad) ^ (n & 7)) * 8 };
    // V b64 read offsets for the slot-key remap: for kc, cc: logical granule
    // 4kc + 2cc + (quad>>1), half (quad&1); physical = logical ^ (n&7).
    const int h4 = (quad & 1) * 4;
    const int q2 = quad >> 1;
    int vswz[2][2];
#pragma unroll
    for (int kc = 0; kc < 2; ++kc)
#pragma unroll
        for (int cc = 0; cc < 2; ++cc)
            vswz[kc][cc] = (((4 * kc + 2 * cc + q2) ^ (n & 7)) << 3) + h4;

    // prologue: stage tile 0 into buffer 0
#pragma unroll
    for (int i = 0; i < 2; ++i) {
        gload_lds16(&Kb[(size_t)(w * 16 + i * 8 + l8) * 64 + sg * 8],
                    &Ksm[0][(w * 16 + i * 8) * 64]);
        gload_lds16(&Vb[(size_t)(w * 16 + i * 8 + l8) * 2048 + sg * 8],
                    &Vsm[0][(w * 16 + i * 8) * 64]);
    }

    for (int kb = 0; kb < S_DIM / 64; ++kb) {
        __syncthreads();   // stage(kb) complete; buf cur^1 free for overwrite
        const int cur = kb & 1;
        if (kb + 1 < S_DIM / 64) {
            const int key1 = (kb + 1) * 64;
            const int nxt  = cur ^ 1;
#pragma unroll
            for (int i = 0; i < 2; ++i) {
                gload_lds16(&Kb[(size_t)(key1 + w * 16 + i * 8 + l8) * 64 + sg * 8],
                            &Ksm[nxt][(w * 16 + i * 8) * 64]);
                gload_lds16(&Vb[(size_t)(w * 16 + i * 8 + l8) * 2048 + key1 + sg * 8],
                            &Vsm[nxt][(w * 16 + i * 8) * 64]);
            }
        }

        // A-frag: lane holds K[key = ct*16+n][d = kc*32+quad*8 ..]
        short8 kf[4][2];
#pragma unroll
        for (int ct = 0; ct < 4; ++ct)
#pragma unroll
            for (int kc = 0; kc < 2; ++kc)
                kf[ct][kc] = *(const short8*)&Ksm[cur][(ct * 16 + n) * 64 + fswz[kc]];

        // S^T[key][q]: s[ct][r] = S[q = qbase+n][key = ct*16+quad*4+r]
        float4v s[4];
#pragma unroll
        for (int ct = 0; ct < 4; ++ct) {
            float4v a = (float4v){0.f, 0.f, 0.f, 0.f};
            a = __builtin_amdgcn_mfma_f32_16x16x32_bf16(kf[ct][0], qa[0], a, 0, 0, 0);
            a = __builtin_amdgcn_mfma_f32_16x16x32_bf16(kf[ct][1], qa[1], a, 0, 0, 0);
            s[ct] = a;
        }

        // B-frag under remap: slot q*8+e holds V[key = 32kc+16(e>>2)+4q+(e&3)]
        // [d = nt*16+n]; two b64 reads concatenated.
        short8 vf[4][2];
#pragma unroll
        for (int nt = 0; nt < 4; ++nt) {
            const int rb = (nt * 16 + n) * 64;
#pragma unroll
            for (int kc = 0; kc < 2; ++kc) {
                const short4v g0 = *(const short4v*)&Vsm[cur][rb + vswz[kc][0]];
                const short4v g1 = *(const short4v*)&Vsm[cur][rb + vswz[kc][1]];
                vf[nt][kc] = __builtin_shufflevector(g0, g1, 0, 1, 2, 3, 4, 5, 6, 7);
            }
        }

        // tile max for q = qbase+n (my 16 keys, then across quads)
        float lm = s[0][0];
#pragma unroll
        for (int ct = 0; ct < 4; ++ct)
#pragma unroll
            for (int r = 0; r < 4; ++r)
                lm = fmaxf(lm, s[ct][r]);
        lm = fmaxf(lm, __shfl_xor(lm, 16, 64));
        lm = fmaxf(lm, __shfl_xor(lm, 32, 64));

        const bool ev = lm > mrow + 8.0f;   // defer-max threshold
        if (__any(ev)) {
            const float mnew  = ev ? lm : mrow;
            const float alpha = fexp2(mrow - mnew);  // 1.0 when !ev
            mrow = mnew;
            lrow *= alpha;
            const int ai = __float_as_int(alpha);
            float av[4];
#pragma unroll
            for (int r = 0; r < 4; ++r)
                av[r] = __int_as_float(
                    __builtin_amdgcn_ds_bpermute(4 * (quad * 4 + r), ai));
#pragma unroll
            for (int nt = 0; nt < 4; ++nt)
#pragma unroll
                for (int r = 0; r < 4; ++r) O[nt][r] *= av[r];
        }

        // P = 2^(s - m); l as local partial (reduced once at the end)
        float pv[4][4];
        float lsum = 0.f;
#pragma unroll
        for (int ct = 0; ct < 4; ++ct)
#pragma unroll
            for (int r = 0; r < 4; ++r) {
                const float p = fexp2(s[ct][r] - mrow);
                pv[ct][r] = p;
                lsum += p;
            }
        lrow += lsum;

        // PV A-frag is PURELY LOCAL under the remap:
        // element e of pk[kc] = pv[2kc + (e>>2)][e&3]; cvt_pk = 1 instr/dword.
        union { unsigned u[4]; short8 s8; } pk[2];
#pragma unroll
        for (int kc = 0; kc < 2; ++kc) {
            pk[kc].u[0] = cvtpk_bf16(pv[2 * kc][0],     pv[2 * kc][1]);
            pk[kc].u[1] = cvtpk_bf16(pv[2 * kc][2],     pv[2 * kc][3]);
            pk[kc].u[2] = cvtpk_bf16(pv[2 * kc + 1][0], pv[2 * kc + 1][1]);
            pk[kc].u[3] = cvtpk_bf16(pv[2 * kc + 1][2], pv[2 * kc + 1][3]);
        }

#pragma unroll
        for (int nt = 0; nt < 4; ++nt) {
            O[nt] = __builtin_amdgcn_mfma_f32_16x16x32_bf16(pk[0].s8, vf[nt][0], O[nt], 0, 0, 0);
            O[nt] = __builtin_amdgcn_mfma_f32_16x16x32_bf16(pk[1].s8, vf[nt][1], O[nt], 0, 0, 0);
        }
    }

    float ls = lrow;
    ls += __shfl_xor(ls, 16, 64);
    ls += __shfl_xor(ls, 32, 64);
    const float linv = 1.f / ls;            // at lane: q = qbase + n
    const int  li = __float_as_int(linv);
    float lv[4];
#pragma unroll
    for (int r = 0; r < 4; ++r)
        lv[r] = __int_as_float(
            __builtin_amdgcn_ds_bpermute(4 * (quad * 4 + r), li));
#pragma unroll
    for (int nt = 0; nt < 4; ++nt)
#pragma unroll
        for (int r = 0; r < 4; ++r) {
            const int q = qbase + quad * 4 + r;
            Yh[((size_t)(b * S_DIM + q) << 10) + h * DH + nt * 16 + n] =
                f2bf(O[nt][r] * lv[r]);
        }
}

// ---------------------------------------------------------------------------
extern "C" void kernel_launch(void* const* d_in, const int* in_sizes, int n_in,
                              void* d_out, int out_size, void* d_ws, size_t ws_size,
                              hipStream_t stream)
{
    const float* x  = (const float*)d_in[0];
    const float* wq = (const float*)d_in[1];
    const float* wk = (const float*)d_in[2];
    const float* wv = (const float*)d_in[3];
    const float* wo = (const float*)d_in[4];
    const float* bo = (const float*)d_in[5];
    float* out = (float*)d_out;

    const size_t MD = (size_t)M_DIM * D_DIM;      // 4M elements
    const size_t WD = (size_t)D_DIM * D_DIM;      // 1M elements
    ushort* xh  = (ushort*)d_ws;      // 8 MB  [M,K] bf16
    ushort* Wh  = xh + MD;            // 6 MB  [3072,1024] bf16 (wq|wk|wv)
    ushort* Woh = Wh + 3 * WD;        // 2 MB  [1024,1024] bf16
    ushort* Qh  = Woh + WD;           // 8 MB  [B,H,S,Dh] bf16 (pre-scaled)
    ushort* Kh  = Qh + MD;            // 8 MB  [B,H,S,Dh] bf16
    ushort* Vt  = Kh + MD;            // 8 MB  [B,H,Dh,S] bf16
    ushort* Yh  = Vt + MD;            // 8 MB  [M,D] bf16
    if (ws_size < 48u * 1024u * 1024u) return;

    dim3 blk(256);
    cast_all<<<dim3(8192), blk, 0, stream>>>(x, wq, wk, wv, wo, xh);

    gemm_bf16<<<dim3(24, 32), blk, 0, stream>>>(xh, Wh, Qh, Kh, Vt, nullptr, nullptr, 0);
    attn_mfma<<<dim3(1024), blk, 0, stream>>>(Qh, Kh, Vt, Yh);
    gemm_bf16<<<dim3(8, 32), blk, 0, stream>>>(Yh, Woh, nullptr, nullptr, nullptr, out, bo, 1);
}

// Round 7
// 217.683 us; speedup vs baseline: 1.1166x; 1.1166x over previous
//
#include <hip/hip_runtime.h>
#include <math.h>

#define B_DIM 2
#define S_DIM 2048
#define D_DIM 1024
#define H_NUM 16
#define DH    64
#define M_DIM (B_DIM * S_DIM) /* 4096 */

typedef __attribute__((ext_vector_type(8))) short short8;
typedef __attribute__((ext_vector_type(4))) short short4v;
typedef __attribute__((ext_vector_type(4))) float float4v;
typedef __attribute__((ext_vector_type(4))) unsigned short ushort4v;
typedef unsigned short ushort;

static __device__ __forceinline__ ushort f2bf(float f) {
    unsigned u = __float_as_uint(f);
    u += 0x7fffu + ((u >> 16) & 1u);
    return (ushort)(u >> 16);
}

static __device__ __forceinline__ float fexp2(float x) {
#if __has_builtin(__builtin_amdgcn_exp2f)
    return __builtin_amdgcn_exp2f(x);
#else
    return exp2f(x);
#endif
}

// 2 f32 -> 2 bf16 in one u32, lo half = first arg. Ordering PROVEN on this
// harness: rounds 3 (cvt_pk) and 4 (explicit lo|hi<<16) gave bit-identical
// outputs.
static __device__ __forceinline__ unsigned cvtpk_bf16(float lo, float hi) {
    unsigned r;
    asm("v_cvt_pk_bf16_f32 %0, %1, %2" : "=v"(r) : "v"(lo), "v"(hi));
    return r;
}

static __device__ __forceinline__ void gload_lds16(const void* g, void* l) {
    __builtin_amdgcn_global_load_lds(
        (const __attribute__((address_space(1))) void*)g,
        (__attribute__((address_space(3))) void*)l, 16, 0, 0);
}

// ---------------------------------------------------------------------------
// Fused fp32 -> bf16 cast of ALL five tensors in one launch.
// dst layout (contiguous in ws): xh[4M] | wq[1M] | wk[1M] | wv[1M] | wo[1M]
// ---------------------------------------------------------------------------
__global__ __launch_bounds__(256)
void cast_all(const float* __restrict__ x,  const float* __restrict__ wq,
              const float* __restrict__ wk, const float* __restrict__ wv,
              const float* __restrict__ wo, ushort* __restrict__ dst)
{
    const int i = blockIdx.x * 256 + threadIdx.x;   // 0 .. 2M-1 (float4 units)
    const float4* s;
    int off;
    if      (i < 1048576) { s = (const float4*)x;  off = 0;       }
    else if (i < 1310720) { s = (const float4*)wq; off = 1048576; }
    else if (i < 1572864) { s = (const float4*)wk; off = 1310720; }
    else if (i < 1835008) { s = (const float4*)wv; off = 1572864; }
    else                  { s = (const float4*)wo; off = 1835008; }
    const float4 v = s[i - off];
    ushort4v o;
    o[0] = f2bf(v.x); o[1] = f2bf(v.y); o[2] = f2bf(v.z); o[3] = f2bf(v.w);
    ((ushort4v*)dst)[i] = o;
}

// ---------------------------------------------------------------------------
// bf16 MFMA GEMM, m97 structure: 128x128 tile, BK=32, global_load_lds w=16,
// 4 waves in 2x2, each wave 64x64 via 4x4 grid of 16x16x32 MFMAs.
// A:[M=4096, K=1024] bf16 row-major. B:[N, K=1024] bf16 row-major.
// mode 0 (N=3072, fused QKV): n>>10 selects dst: 0->Qh [B,H,S,Dh]
//        (PRE-SCALED by 0.125*log2e for base-2 online softmax),
//        1->Kh [B,H,S,Dh], 2->Vt [B,H,Dh,S]; all bf16.
// mode 1 (N=1024, out proj): fp32 out[m*1024+n] = acc + bias[n].
// ---------------------------------------------------------------------------
__global__ __launch_bounds__(256)
void gemm_bf16(const ushort* __restrict__ A, const ushort* __restrict__ B,
               ushort* __restrict__ Qh, ushort* __restrict__ Kh,
               ushort* __restrict__ Vt, float* __restrict__ Of,
               const float* __restrict__ bias, int mode)
{
    __shared__ ushort Asm[128 * 32];   // [row][k], 64B rows, lane-order (no pad!)
    __shared__ ushort Bsm[128 * 32];

    const int K  = 1024;
    const int n0 = blockIdx.x * 128;
    const int m0 = blockIdx.y * 128;
    const int t    = threadIdx.x;
    const int w    = t >> 6;
    const int lane = t & 63;
    const int n    = lane & 15;
    const int quad = lane >> 4;
    const int wm = w >> 1, wn = w & 1;

    const int srow = w * 32 + (lane >> 2);
    const int skel = (lane & 3) * 8;

    float4v acc[4][4];
#pragma unroll
    for (int mt = 0; mt < 4; ++mt)
#pragma unroll
        for (int nt = 0; nt < 4; ++nt) acc[mt][nt] = (float4v){0.f, 0.f, 0.f, 0.f};

    for (int kt = 0; kt < K; kt += 32) {
#pragma unroll
        for (int i = 0; i < 2; ++i) {
            gload_lds16(&A[(size_t)(m0 + srow + i * 16) * K + kt + skel],
                        &Asm[(w * 2 + i) * 512]);
            gload_lds16(&B[(size_t)(n0 + srow + i * 16) * K + kt + skel],
                        &Bsm[(w * 2 + i) * 512]);
        }
        __syncthreads();

        short8 af[4], bfr[4];
#pragma unroll
        for (int mt = 0; mt < 4; ++mt)
            af[mt] = *(const short8*)&Asm[(wm * 64 + mt * 16 + n) * 32 + quad * 8];
#pragma unroll
        for (int nt = 0; nt < 4; ++nt)
            bfr[nt] = *(const short8*)&Bsm[(wn * 64 + nt * 16 + n) * 32 + quad * 8];

#pragma unroll
        for (int mt = 0; mt < 4; ++mt)
#pragma unroll
            for (int nt = 0; nt < 4; ++nt)
                acc[mt][nt] = __builtin_amdgcn_mfma_f32_16x16x32_bf16(
                    af[mt], bfr[nt], acc[mt][nt], 0, 0, 0);
        __syncthreads();
    }

    if (mode == 0) {
        const int wid = n0 >> 10;           // 0=Q 1=K 2=V (constant per block)
        ushort* dstQK = (wid == 0) ? Qh : Kh;
        const float qs = (wid == 0) ? 0.1803368801f : 1.0f;  // 0.125*log2(e)
#pragma unroll
        for (int mt = 0; mt < 4; ++mt) {
            const int m = m0 + wm * 64 + mt * 16 + quad * 4;   // +r
            const int b = m >> 11, s = m & (S_DIM - 1);
#pragma unroll
            for (int nt = 0; nt < 4; ++nt) {
                const int ng = (n0 & 1023) + wn * 64 + nt * 16 + n;
                const int h = ng >> 6, d = ng & 63;
                const int bh = b * H_NUM + h;
                if (wid < 2) {
#pragma unroll
                    for (int r = 0; r < 4; ++r)
                        dstQK[(((size_t)bh * S_DIM + s + r) << 6) + d] =
                            f2bf(acc[mt][nt][r] * qs);
                } else {
                    ushort4v p;
#pragma unroll
                    for (int r = 0; r < 4; ++r) p[r] = f2bf(acc[mt][nt][r]);
                    *(ushort4v*)&Vt[(((size_t)bh * DH + d) << 11) + s] = p;
                }
            }
        }
    } else {
#pragma unroll
        for (int mt = 0; mt < 4; ++mt) {
            const int m = m0 + wm * 64 + mt * 16 + quad * 4;
#pragma unroll
            for (int nt = 0; nt < 4; ++nt) {
                const int ng = n0 + wn * 64 + nt * 16 + n;
                const float bv = bias[ng];
#pragma unroll
                for (int r = 0; r < 4; ++r)
                    Of[(size_t)(m + r) * D_DIM + ng] = acc[mt][nt][r] + bv;
            }
        }
    }
}

// ---------------------------------------------------------------------------
// MFMA flash attention: round-5 geometry (32 q-rows/wave, 512 blocks --
// round 6 proved per-wave K/V LDS reads don't scale down with Q-rows, so
// bigger Q-tiles win) + cvt_pk P-packing (round 6 proved the VALU cut:
// VGPR 104->72) + s_setprio around MFMA clusters (T5).
// Swapped QK^T, fully LOCAL P->PV handoff via the free k-slot->key remap
// slot q*8+e <-> key 32kc+16(e>>2)+4q+(e&3) (A and B use the same map).
// Defer-max (THR=8, base-2); Q pre-scaled by 0.125*log2e.
// ---------------------------------------------------------------------------
__global__ __launch_bounds__(256)
void attn_mfma(const ushort* __restrict__ Qh, const ushort* __restrict__ Kh,
               const ushort* __restrict__ Vt, ushort* __restrict__ Yh)
{
    __shared__ ushort Ksm[2][64 * 64];   // [buf][key 64][d 64] granule-swizzled
    __shared__ ushort Vsm[2][64 * 64];   // [buf][d 64][key 64] granule-swizzled

    const int w    = threadIdx.x >> 6;
    const int lane = threadIdx.x & 63;
    const int n    = lane & 15;
    const int quad = lane >> 4;

    const int wave_id = blockIdx.x * 4 + w;
    const int bh    = wave_id >> 6;          // all 4 waves of a block: same bh
    const int qbase = (wave_id & 63) * 32;
    const int b     = bh >> 4;
    const int h     = bh & (H_NUM - 1);

    const ushort* Qb = Qh + (((size_t)bh * S_DIM) << 6);
    const ushort* Kb = Kh + (((size_t)bh * S_DIM) << 6);
    const ushort* Vb = Vt + (((size_t)bh * DH) << 11);

    // staging: lane l covers row sub-index l>>3, 16B granule (l&7), source
    // granule pre-swizzled (gload_lds dst must stay linear).
    const int l8 = lane >> 3;
    const int sg = (lane & 7) ^ l8;

    short8 qa[2][2];   // B-frag: lane holds Q[q = mt*16+n][d = kc*32+quad*8 ..]
#pragma unroll
    for (int mt = 0; mt < 2; ++mt)
#pragma unroll
        for (int kc = 0; kc < 2; ++kc)
            qa[mt][kc] = *(const short8*)&Qb[((size_t)(qbase + mt * 16 + n) << 6) + kc * 32 + quad * 8];

    float4v O[2][4];           // O[mt][nt][r]: q = mt*16+quad*4+r, d = nt*16+n
    float   mrow[2], lrow[2];  // per-lane: q = mt*16 + n (uniform over quads)
#pragma unroll
    for (int mt = 0; mt < 2; ++mt) {
#pragma unroll
        for (int nt = 0; nt < 4; ++nt) O[mt][nt] = (float4v){0.f, 0.f, 0.f, 0.f};
        mrow[mt] = -1e30f; lrow[mt] = 0.f;
    }

    // K fragment-read offsets (ushort units): logical granule g at row rr is
    // stored at physical g ^ (rr&7); rr&7 == n&7 for rr = ct*16 + n.
    const int fswz[2] = { ((0 * 4 + quad) ^ (n & 7)) * 8,
                          ((1 * 4 + quad) ^ (n & 7)) * 8 };
    // V b64 read offsets for the slot-key remap: for kc, cc: logical granule
    // 4kc + 2cc + (quad>>1), half (quad&1); physical = logical ^ (n&7).
    const int h4 = (quad & 1) * 4;
    const int q2 = quad >> 1;
    int vswz[2][2];
#pragma unroll
    for (int kc = 0; kc < 2; ++kc)
#pragma unroll
        for (int cc = 0; cc < 2; ++cc)
            vswz[kc][cc] = (((4 * kc + 2 * cc + q2) ^ (n & 7)) << 3) + h4;

    // prologue: stage tile 0 into buffer 0
#pragma unroll
    for (int i = 0; i < 2; ++i) {
        gload_lds16(&Kb[(size_t)(w * 16 + i * 8 + l8) * 64 + sg * 8],
                    &Ksm[0][(w * 16 + i * 8) * 64]);
        gload_lds16(&Vb[(size_t)(w * 16 + i * 8 + l8) * 2048 + sg * 8],
                    &Vsm[0][(w * 16 + i * 8) * 64]);
    }

    for (int kb = 0; kb < S_DIM / 64; ++kb) {
        __syncthreads();   // stage(kb) complete; buf cur^1 free for overwrite
        const int cur = kb & 1;
        if (kb + 1 < S_DIM / 64) {
            const int key1 = (kb + 1) * 64;
            const int nxt  = cur ^ 1;
#pragma unroll
            for (int i = 0; i < 2; ++i) {
                gload_lds16(&Kb[(size_t)(key1 + w * 16 + i * 8 + l8) * 64 + sg * 8],
                            &Ksm[nxt][(w * 16 + i * 8) * 64]);
                gload_lds16(&Vb[(size_t)(w * 16 + i * 8 + l8) * 2048 + key1 + sg * 8],
                            &Vsm[nxt][(w * 16 + i * 8) * 64]);
            }
        }

        // A-frag: lane holds K[key = ct*16+n][d = kc*32+quad*8 ..]
        short8 kf[4][2];
#pragma unroll
        for (int ct = 0; ct < 4; ++ct)
#pragma unroll
            for (int kc = 0; kc < 2; ++kc)
                kf[ct][kc] = *(const short8*)&Ksm[cur][(ct * 16 + n) * 64 + fswz[kc]];

        // S^T[key][q]: s[mt][ct][r] = S[q = mt*16+n][key = ct*16+quad*4+r]
        float4v s[2][4];
        __builtin_amdgcn_s_setprio(1);
#pragma unroll
        for (int mt = 0; mt < 2; ++mt)
#pragma unroll
            for (int ct = 0; ct < 4; ++ct) {
                float4v a = (float4v){0.f, 0.f, 0.f, 0.f};
                a = __builtin_amdgcn_mfma_f32_16x16x32_bf16(kf[ct][0], qa[mt][0], a, 0, 0, 0);
                a = __builtin_amdgcn_mfma_f32_16x16x32_bf16(kf[ct][1], qa[mt][1], a, 0, 0, 0);
                s[mt][ct] = a;
            }
        __builtin_amdgcn_s_setprio(0);

        // B-frag under remap: slot q*8+e holds V[key = 32kc+16(e>>2)+4q+(e&3)]
        // [d = nt*16+n]; two b64 reads concatenated.
        short8 vf[4][2];
#pragma unroll
        for (int nt = 0; nt < 4; ++nt) {
            const int rb = (nt * 16 + n) * 64;
#pragma unroll
            for (int kc = 0; kc < 2; ++kc) {
                const short4v g0 = *(const short4v*)&Vsm[cur][rb + vswz[kc][0]];
                const short4v g1 = *(const short4v*)&Vsm[cur][rb + vswz[kc][1]];
                vf[nt][kc] = __builtin_shufflevector(g0, g1, 0, 1, 2, 3, 4, 5, 6, 7);
            }
        }

#pragma unroll
        for (int mt = 0; mt < 2; ++mt) {
            // tile max for q = mt*16+n (my 16 keys, then across quads)
            float lm = s[mt][0][0];
#pragma unroll
            for (int ct = 0; ct < 4; ++ct)
#pragma unroll
                for (int r = 0; r < 4; ++r)
                    lm = fmaxf(lm, s[mt][ct][r]);
            lm = fmaxf(lm, __shfl_xor(lm, 16, 64));
            lm = fmaxf(lm, __shfl_xor(lm, 32, 64));

            const bool ev = lm > mrow[mt] + 8.0f;   // defer-max threshold
            if (__any(ev)) {
                const float mnew  = ev ? lm : mrow[mt];
                const float alpha = fexp2(mrow[mt] - mnew);  // 1.0 when !ev
                mrow[mt] = mnew;
                lrow[mt] *= alpha;
                const int ai = __float_as_int(alpha);
                float av[4];
#pragma unroll
                for (int r = 0; r < 4; ++r)
                    av[r] = __int_as_float(
                        __builtin_amdgcn_ds_bpermute(4 * (quad * 4 + r), ai));
#pragma unroll
                for (int nt = 0; nt < 4; ++nt)
#pragma unroll
                    for (int r = 0; r < 4; ++r) O[mt][nt][r] *= av[r];
            }

            // P = 2^(s - m); l as local partial (reduced once at the end)
            float pv[4][4];
            float lsum = 0.f;
#pragma unroll
            for (int ct = 0; ct < 4; ++ct)
#pragma unroll
                for (int r = 0; r < 4; ++r) {
                    const float p = fexp2(s[mt][ct][r] - mrow[mt]);
                    pv[ct][r] = p;
                    lsum += p;
                }
            lrow[mt] += lsum;

            // PV A-frag is PURELY LOCAL under the remap:
            // element e of pk[kc] = pv[2kc + (e>>2)][e&3]; cvt_pk = 1 instr.
            union { unsigned u[4]; short8 s8; } pk[2];
#pragma unroll
            for (int kc = 0; kc < 2; ++kc) {
                pk[kc].u[0] = cvtpk_bf16(pv[2 * kc][0],     pv[2 * kc][1]);
                pk[kc].u[1] = cvtpk_bf16(pv[2 * kc][2],     pv[2 * kc][3]);
                pk[kc].u[2] = cvtpk_bf16(pv[2 * kc + 1][0], pv[2 * kc + 1][1]);
                pk[kc].u[3] = cvtpk_bf16(pv[2 * kc + 1][2], pv[2 * kc + 1][3]);
            }

            __builtin_amdgcn_s_setprio(1);
#pragma unroll
            for (int nt = 0; nt < 4; ++nt) {
                O[mt][nt] = __builtin_amdgcn_mfma_f32_16x16x32_bf16(pk[0].s8, vf[nt][0], O[mt][nt], 0, 0, 0);
                O[mt][nt] = __builtin_amdgcn_mfma_f32_16x16x32_bf16(pk[1].s8, vf[nt][1], O[mt][nt], 0, 0, 0);
            }
            __builtin_amdgcn_s_setprio(0);
        }
    }

#pragma unroll
    for (int mt = 0; mt < 2; ++mt) {
        float ls = lrow[mt];
        ls += __shfl_xor(ls, 16, 64);
        ls += __shfl_xor(ls, 32, 64);
        const float linv = 1.f / ls;            // at lane: q = mt*16 + n
        const int  li = __float_as_int(linv);
        float lv[4];
#pragma unroll
        for (int r = 0; r < 4; ++r)
            lv[r] = __int_as_float(
                __builtin_amdgcn_ds_bpermute(4 * (quad * 4 + r), li));
#pragma unroll
        for (int nt = 0; nt < 4; ++nt)
#pragma unroll
            for (int r = 0; r < 4; ++r) {
                const int q = qbase + mt * 16 + quad * 4 + r;
                Yh[((size_t)(b * S_DIM + q) << 10) + h * DH + nt * 16 + n] =
                    f2bf(O[mt][nt][r] * lv[r]);
            }
    }
}

// ---------------------------------------------------------------------------
extern "C" void kernel_launch(void* const* d_in, const int* in_sizes, int n_in,
                              void* d_out, int out_size, void* d_ws, size_t ws_size,
                              hipStream_t stream)
{
    const float* x  = (const float*)d_in[0];
    const float* wq = (const float*)d_in[1];
    const float* wk = (const float*)d_in[2];
    const float* wv = (const float*)d_in[3];
    const float* wo = (const float*)d_in[4];
    const float* bo = (const float*)d_in[5];
    float* out = (float*)d_out;

    const size_t MD = (size_t)M_DIM * D_DIM;      // 4M elements
    const size_t WD = (size_t)D_DIM * D_DIM;      // 1M elements
    ushort* xh  = (ushort*)d_ws;      // 8 MB  [M,K] bf16
    ushort* Wh  = xh + MD;            // 6 MB  [3072,1024] bf16 (wq|wk|wv)
    ushort* Woh = Wh + 3 * WD;        // 2 MB  [1024,1024] bf16
    ushort* Qh  = Woh + WD;           // 8 MB  [B,H,S,Dh] bf16 (pre-scaled)
    ushort* Kh  = Qh + MD;            // 8 MB  [B,H,S,Dh] bf16
    ushort* Vt  = Kh + MD;            // 8 MB  [B,H,Dh,S] bf16
    ushort* Yh  = Vt + MD;            // 8 MB  [M,D] bf16
    if (ws_size < 48u * 1024u * 1024u) return;

    dim3 blk(256);
    cast_all<<<dim3(8192), blk, 0, stream>>>(x, wq, wk, wv, wo, xh);

    gemm_bf16<<<dim3(24, 32), blk, 0, stream>>>(xh, Wh, Qh, Kh, Vt, nullptr, nullptr, 0);
    attn_mfma<<<dim3(512), blk, 0, stream>>>(Qh, Kh, Vt, Yh);
    gemm_bf16<<<dim3(8, 32), blk, 0, stream>>>(Yh, Woh, nullptr, nullptr, nullptr, out, bo, 1);
}